// Round 9
// baseline (653.492 us; speedup 1.0000x reference)
//
#include <hip/hip_runtime.h>
#include <hip/hip_bf16.h>

#define B_N    16
#define C_IN   64
#define QDIM   576
#define OC     128
#define M_TOT  36864
#define PLANE  2512   // 50*50 = 2500 padded to multiple of 8 for 16B stores
#define BM     192
#define NSTEP  21     // per k-quarter; K padded 81 -> 84 tiles (81..83 are zero W)

typedef __attribute__((ext_vector_type(8))) short short8;
typedef __attribute__((ext_vector_type(4))) float floatx4;

__device__ __forceinline__ unsigned short f2bf(float f) {
    union { float f; unsigned u; } v; v.f = f;
    unsigned r = (v.u + 0x7FFFu + ((v.u >> 16) & 1u)) >> 16;
    return (unsigned short)r;
}

// phi[0]=silu(x); phi[1..8]=cubic B-spline bases, uniform grid [-2.2..2.2], h=0.4.
__device__ __forceinline__ void compute_phi(float x, float* phi) {
    phi[0] = x * __builtin_amdgcn_rcpf(1.0f + __expf(-x));
    float t[12];
#pragma unroll
    for (int i = 0; i < 12; ++i) t[i] = 0.4f * (float)(i - 3) - 1.0f;
    float bb[11];
#pragma unroll
    for (int j = 0; j < 11; ++j) bb[j] = (x >= t[j] && x < t[j + 1]) ? 1.0f : 0.0f;
#pragma unroll
    for (int j = 0; j < 10; ++j)
        bb[j] = (x - t[j]) * 2.5f * bb[j] + (t[j + 2] - x) * 2.5f * bb[j + 1];
#pragma unroll
    for (int j = 0; j < 9; ++j)
        bb[j] = (x - t[j]) * 1.25f * bb[j] + (t[j + 3] - x) * 1.25f * bb[j + 1];
#pragma unroll
    for (int j = 0; j < 8; ++j)
        bb[j] = (x - t[j]) * (2.5f / 3.0f) * bb[j] + (t[j + 4] - x) * (2.5f / 3.0f) * bb[j + 1];
#pragma unroll
    for (int g = 0; g < 8; ++g) phi[1 + g] = bb[g];
}

// Fused prep: blocks 0..287 = weight pack (+ zero W tiles 81..83); blocks 288.. = phi.
// Wp tile kt (16KB): addr = kt*16384 + wo*4096 + ks*2048 + fo*1024 + (hi8*16+lo)*16 + e*2
//   where oc = wo*32+fo*16+lo, kk = ks*32+hi8*8+e.  Lane fragment = contiguous 16B.
__global__ __launch_bounds__(256) void prep_kernel(const float* __restrict__ x,
                                                   const float* __restrict__ bw,
                                                   const float* __restrict__ sw,
                                                   const float* __restrict__ sc,
                                                   unsigned short* __restrict__ Wp,
                                                   unsigned short* __restrict__ Phi) {
    int bid = blockIdx.x;
    if (bid < 288) {
        int gtid = bid * 256 + threadIdx.x;      // oc*576 + q ; 73728 total
        if (gtid < 6144) {                        // zero W tiles 81..83 (48KB, 8B/thread)
            *(unsigned long long*)((unsigned char*)Wp + 81 * 16384 + gtid * 8) = 0ull;
        }
        int oc = gtid / QDIM, q = gtid - oc * QDIM;
        float base = bw[gtid];
        float scal = sc[gtid];
        unsigned char* wp8 = (unsigned char*)Wp;
        int kk = q & 63;
        int wo = oc >> 5, fo = (oc >> 4) & 1, lo = oc & 15;
        int ks = kk >> 5, hi8 = (kk >> 3) & 3, e = kk & 7;
        int inner = wo * 4096 + ks * 2048 + fo * 1024 + (hi8 * 16 + lo) * 16 + e * 2;
        int ktb = q >> 6;
        *(unsigned short*)(wp8 + (size_t)ktb * 16384 + inner) = f2bf(base);
#pragma unroll
        for (int g = 0; g < 8; ++g) {
            float v = sw[(size_t)gtid * 8 + g] * scal;
            *(unsigned short*)(wp8 + (size_t)((g + 1) * 9 + ktb) * 16384 + inner) = f2bf(v);
        }
    } else {
        int ch = (bid - 288) * 256 + threadIdx.x;  // 1024 bc * 314 chunks
        int bc = ch / 314;
        int cp = ch - bc * 314;
        int p0 = cp * 8;
        const float* xsrc = x + (size_t)bc * 2304;
        short8 v[9];
#pragma unroll
        for (int e = 0; e < 8; ++e) {
            int p = p0 + e;
            int hh = p / 50;
            int ww = p - hh * 50;
            float xv = (hh >= 1 && hh <= 48 && ww >= 1 && ww <= 48) ? xsrc[(hh - 1) * 48 + (ww - 1)] : 0.0f;
            float phi[9];
            compute_phi(xv, phi);
#pragma unroll
            for (int j = 0; j < 9; ++j) v[j][e] = (short)f2bf(phi[j]);
        }
        unsigned short* pdst = Phi + (size_t)bc * 9 * PLANE + p0;
#pragma unroll
        for (int j = 0; j < 9; ++j) *(short8*)(pdst + (size_t)j * PLANE) = v[j];
    }
}

#define MFMA_BF16 __builtin_amdgcn_mfma_f32_16x16x32_bf16

// GEMM split-K x4: out[n][oc] += sum_k A[n][k]*W[k][oc]. M=36864, N=128, K=5184.
// BM=192, BN=128, BK=64; grid = 192 M-tiles x 4 k-quarters = 768 blocks (512 thr)
// = 3 blocks/CU, 24 waves/CU. 8 waves = 2 m-halves x 4 oc-quarters; per-wave tile
// 96m x 32oc x BK64, acc[6][2] (round-6 geometry). W -> named regs dbuf from L2;
// A -> LDS dbuf 24KB/step via global_load_lds. Epilogue: atomicAdd (out pre-zeroed);
// 4 commutative f32 contributions per element.
__global__ __launch_bounds__(512, 6) void gemm_kernel(const unsigned short* __restrict__ Phi,
                                                      const unsigned short* __restrict__ Wp,
                                                      float* __restrict__ out) {
    __shared__ __align__(16) unsigned char lds[49152]; // A dbuf 2 x 24KB
    int bid = blockIdx.x;
    int swz = (bid & 7) * 96 + (bid >> 3);   // XCD-bijective (768 = 8*96)
    int tile = swz >> 2, kq = swz & 3;
    int m0 = tile * BM;
    int kt0 = kq * NSTEP;                     // 0, 21, 42, 63
    int tid = threadIdx.x;
    int lane = tid & 63;
    int wv = tid >> 6;                        // 0..7
    int wm = wv >> 2;                         // m-half
    int wo = wv & 3;                          // oc-quarter
    int lo = lane & 15, hi = lane >> 4, l7 = lane & 7;

    // A staging: 192 rows x 8 chunks = 1536 chunks; thread stages rows r0, r0+64, r0+128.
    int s8 = tid & 7;
    int r0 = tid >> 3;                        // 0..63
    int sx = s8 ^ (r0 & 7);                   // same for all three rows (64-spaced)
    size_t rowb[3];
#pragma unroll
    for (int i = 0; i < 3; ++i) {
        int n  = m0 + r0 + 64 * i;
        int b  = n / 2304;
        int u  = n - b * 2304;
        int du = u >> 2;                      // patches feature (c,kh,kw)
        int rr = u & 3;                       // 576-chunk within reinterpreted row
        int c  = du / 9;
        int tap = du - c * 9;
        int th = tap / 3, tw = tap - th * 3;
        rowb[i] = ((size_t)(b * C_IN + c) * 9) * PLANE + (size_t)((rr * 12 + th) * 50 + tw);
    }

    auto stageA = [&](int sel, int kt) {
        kt = min(kt, 80);                     // padded steps re-read A(80); W is zero there
        int j  = kt / 9;
        int q0 = (kt - j * 9) << 6;
        int qs = q0 + sx * 8;
        int hq = qs / 48, wq = qs - hq * 48;  // 16B chunk never crosses 48-wrap
        size_t delta = (size_t)j * PLANE + (size_t)(hq * 50 + wq);
        unsigned char* pb = lds + sel * 24576;
#pragma unroll
        for (int i = 0; i < 3; ++i) {
            const unsigned short* src = Phi + rowb[i] + delta;
            __builtin_amdgcn_global_load_lds((const __attribute__((address_space(1))) void*)src,
                                             (__attribute__((address_space(3))) void*)(pb + i * 8192 + tid * 16), 16, 0, 0);
        }
    };

    const unsigned char* wsrc = (const unsigned char*)Wp + (size_t)wo * 4096 + (size_t)lane * 16;

#define LOADW(W00, W01, W10, W11, KT) do {                                  \
        const unsigned char* s_ = wsrc + (size_t)(KT) * 16384;              \
        W00 = *(const short8*)(s_);                                         \
        W01 = *(const short8*)(s_ + 1024);                                  \
        W10 = *(const short8*)(s_ + 2048);                                  \
        W11 = *(const short8*)(s_ + 3072);                                  \
    } while (0)

#define HALF(PB, SXR, WA, WB) do {                                          \
        short8 a0_ = *(const short8*)((PB) + ar0 + (SXR));                  \
        short8 a1_ = *(const short8*)((PB) + ar1 + (SXR));                  \
        short8 a2_ = *(const short8*)((PB) + ar2 + (SXR));                  \
        short8 a3_ = *(const short8*)((PB) + ar3 + (SXR));                  \
        short8 a4_ = *(const short8*)((PB) + ar4 + (SXR));                  \
        short8 a5_ = *(const short8*)((PB) + ar5 + (SXR));                  \
        __builtin_amdgcn_s_setprio(1);                                      \
        acc[0][0] = MFMA_BF16(a0_, WA, acc[0][0], 0, 0, 0);                 \
        acc[0][1] = MFMA_BF16(a0_, WB, acc[0][1], 0, 0, 0);                 \
        acc[1][0] = MFMA_BF16(a1_, WA, acc[1][0], 0, 0, 0);                 \
        acc[1][1] = MFMA_BF16(a1_, WB, acc[1][1], 0, 0, 0);                 \
        acc[2][0] = MFMA_BF16(a2_, WA, acc[2][0], 0, 0, 0);                 \
        acc[2][1] = MFMA_BF16(a2_, WB, acc[2][1], 0, 0, 0);                 \
        acc[3][0] = MFMA_BF16(a3_, WA, acc[3][0], 0, 0, 0);                 \
        acc[3][1] = MFMA_BF16(a3_, WB, acc[3][1], 0, 0, 0);                 \
        acc[4][0] = MFMA_BF16(a4_, WA, acc[4][0], 0, 0, 0);                 \
        acc[4][1] = MFMA_BF16(a4_, WB, acc[4][1], 0, 0, 0);                 \
        acc[5][0] = MFMA_BF16(a5_, WA, acc[5][0], 0, 0, 0);                 \
        acc[5][1] = MFMA_BF16(a5_, WB, acc[5][1], 0, 0, 0);                 \
        __builtin_amdgcn_s_setprio(0);                                      \
    } while (0)

#define COMPUTE(SEL, W00, W01, W10, W11) do {                               \
        const unsigned char* pb_ = lds + (SEL) * 24576;                     \
        HALF(pb_, sxr0, W00, W01);                                          \
        HALF(pb_, sxr1, W10, W11);                                          \
    } while (0)

    floatx4 acc[6][2];
    floatx4 zz = {0.f, 0.f, 0.f, 0.f};
#pragma unroll
    for (int a = 0; a < 6; ++a) { acc[a][0] = zz; acc[a][1] = zz; }

    int sxr0 = (hi ^ l7) << 4;               // k-slice 0 chunk slot (row&7 == lo&7 == l7)
    int sxr1 = ((4 + hi) ^ l7) << 4;         // k-slice 1
    int wb0 = wm * 96 * 128;
    int ar0 = wb0 + (0 * 16 + lo) * 128, ar1 = wb0 + (1 * 16 + lo) * 128, ar2 = wb0 + (2 * 16 + lo) * 128;
    int ar3 = wb0 + (3 * 16 + lo) * 128, ar4 = wb0 + (4 * 16 + lo) * 128, ar5 = wb0 + (5 * 16 + lo) * 128;

    short8 u00, u01, u10, u11, v00, v01, v10, v11;
    stageA(0, kt0);
    LOADW(u00, u01, u10, u11, kt0);
    __syncthreads();
    for (int t = 0; t < NSTEP - 1; t += 2) {
        stageA(1, kt0 + t + 1);
        LOADW(v00, v01, v10, v11, kt0 + t + 1);
        COMPUTE(0, u00, u01, u10, u11);
        __syncthreads();
        stageA(0, kt0 + t + 2);
        LOADW(u00, u01, u10, u11, kt0 + t + 2);
        COMPUTE(1, v00, v01, v10, v11);
        __syncthreads();
    }
    COMPUTE(0, u00, u01, u10, u11);           // step NSTEP-1

    // Epilogue: atomicAdd into pre-zeroed out; 4 commutative f32 contributions
    // per element (one per k-quarter). Ordering variance ~ulp, far under threshold.
#pragma unroll
    for (int fm = 0; fm < 6; ++fm) {
#pragma unroll
        for (int fo = 0; fo < 2; ++fo) {
            int oc = wo * 32 + fo * 16 + lo;
            int n0 = m0 + wm * 96 + fm * 16 + hi * 4;
            float* op = out + (size_t)n0 * 128 + oc;
#pragma unroll
            for (int r = 0; r < 4; ++r)
                atomicAdd(op + (size_t)r * 128, acc[fm][fo][r]);
        }
    }
#undef LOADW
#undef HALF
#undef COMPUTE
}

extern "C" void kernel_launch(void* const* d_in, const int* in_sizes, int n_in,
                              void* d_out, int out_size, void* d_ws, size_t ws_size,
                              hipStream_t stream) {
    const float* x  = (const float*)d_in[0];
    const float* bw = (const float*)d_in[1];
    const float* sw = (const float*)d_in[2];
    const float* sc = (const float*)d_in[3];
    float* out = (float*)d_out;

    unsigned short* Wp  = (unsigned short*)d_ws;                         // 84*16KB = 1.31 MB
    unsigned short* Phi = (unsigned short*)((char*)d_ws + 1572864);      // 46.3 MB

    prep_kernel<<<1544, 256, 0, stream>>>(x, bw, sw, sc, Wp, Phi);
    hipMemsetAsync(out, 0, (size_t)out_size * sizeof(float), stream);
    gemm_kernel<<<768, 512, 0, stream>>>(Phi, Wp, out);
}

// Round 10
// 175.705 us; speedup vs baseline: 3.7193x; 3.7193x over previous
//
#include <hip/hip_runtime.h>
#include <hip/hip_bf16.h>

#define B_N    16
#define C_IN   64
#define QDIM   576
#define OC     128
#define M_TOT  36864
#define PLANE  2512   // 50*50 = 2500 padded to multiple of 8 for 16B stores
#define BM     96
#define NSTEP  21     // per k-quarter; K padded 81 -> 84 tiles (81..83 zero W)

typedef __attribute__((ext_vector_type(8))) short short8;
typedef __attribute__((ext_vector_type(4))) float floatx4;

__device__ __forceinline__ unsigned short f2bf(float f) {
    union { float f; unsigned u; } v; v.f = f;
    unsigned r = (v.u + 0x7FFFu + ((v.u >> 16) & 1u)) >> 16;
    return (unsigned short)r;
}

// phi[0]=silu(x); phi[1..8]=cubic B-spline bases, uniform grid [-2.2..2.2], h=0.4.
__device__ __forceinline__ void compute_phi(float x, float* phi) {
    phi[0] = x * __builtin_amdgcn_rcpf(1.0f + __expf(-x));
    float t[12];
#pragma unroll
    for (int i = 0; i < 12; ++i) t[i] = 0.4f * (float)(i - 3) - 1.0f;
    float bb[11];
#pragma unroll
    for (int j = 0; j < 11; ++j) bb[j] = (x >= t[j] && x < t[j + 1]) ? 1.0f : 0.0f;
#pragma unroll
    for (int j = 0; j < 10; ++j)
        bb[j] = (x - t[j]) * 2.5f * bb[j] + (t[j + 2] - x) * 2.5f * bb[j + 1];
#pragma unroll
    for (int j = 0; j < 9; ++j)
        bb[j] = (x - t[j]) * 1.25f * bb[j] + (t[j + 3] - x) * 1.25f * bb[j + 1];
#pragma unroll
    for (int j = 0; j < 8; ++j)
        bb[j] = (x - t[j]) * (2.5f / 3.0f) * bb[j] + (t[j + 4] - x) * (2.5f / 3.0f) * bb[j + 1];
#pragma unroll
    for (int g = 0; g < 8; ++g) phi[1 + g] = bb[g];
}

// Fused prep: blocks 0..287 = weight pack (+ zero W tiles 81..83); blocks 288.. = phi.
// Wp tile kt (16KB): addr = kt*16384 + wo*4096 + ks*2048 + fo*1024 + (hi8*16+lo)*16 + e*2
//   where oc = wo*32+fo*16+lo, kk = ks*32+hi8*8+e.  Lane fragment = contiguous 16B.
__global__ __launch_bounds__(256) void prep_kernel(const float* __restrict__ x,
                                                   const float* __restrict__ bw,
                                                   const float* __restrict__ sw,
                                                   const float* __restrict__ sc,
                                                   unsigned short* __restrict__ Wp,
                                                   unsigned short* __restrict__ Phi) {
    int bid = blockIdx.x;
    if (bid < 288) {
        int gtid = bid * 256 + threadIdx.x;      // oc*576 + q ; 73728 total
        if (gtid < 6144) {                        // zero W tiles 81..83 (48KB, 8B/thread)
            *(unsigned long long*)((unsigned char*)Wp + 81 * 16384 + gtid * 8) = 0ull;
        }
        int oc = gtid / QDIM, q = gtid - oc * QDIM;
        float base = bw[gtid];
        float scal = sc[gtid];
        unsigned char* wp8 = (unsigned char*)Wp;
        int kk = q & 63;
        int wo = oc >> 5, fo = (oc >> 4) & 1, lo = oc & 15;
        int ks = kk >> 5, hi8 = (kk >> 3) & 3, e = kk & 7;
        int inner = wo * 4096 + ks * 2048 + fo * 1024 + (hi8 * 16 + lo) * 16 + e * 2;
        int ktb = q >> 6;
        *(unsigned short*)(wp8 + (size_t)ktb * 16384 + inner) = f2bf(base);
#pragma unroll
        for (int g = 0; g < 8; ++g) {
            float v = sw[(size_t)gtid * 8 + g] * scal;
            *(unsigned short*)(wp8 + (size_t)((g + 1) * 9 + ktb) * 16384 + inner) = f2bf(v);
        }
    } else {
        int ch = (bid - 288) * 256 + threadIdx.x;  // 1024 bc * 314 chunks
        int bc = ch / 314;
        int cp = ch - bc * 314;
        int p0 = cp * 8;
        const float* xsrc = x + (size_t)bc * 2304;
        short8 v[9];
#pragma unroll
        for (int e = 0; e < 8; ++e) {
            int p = p0 + e;
            int hh = p / 50;
            int ww = p - hh * 50;
            float xv = (hh >= 1 && hh <= 48 && ww >= 1 && ww <= 48) ? xsrc[(hh - 1) * 48 + (ww - 1)] : 0.0f;
            float phi[9];
            compute_phi(xv, phi);
#pragma unroll
            for (int j = 0; j < 9; ++j) v[j][e] = (short)f2bf(phi[j]);
        }
        unsigned short* pdst = Phi + (size_t)bc * 9 * PLANE + p0;
#pragma unroll
        for (int j = 0; j < 9; ++j) *(short8*)(pdst + (size_t)j * PLANE) = v[j];
    }
}

#define MFMA_BF16 __builtin_amdgcn_mfma_f32_16x16x32_bf16

// GEMM split-K x4: out[n][oc] += sum_k A[n][k]*W[k][oc]. M=36864, N=128, K=5184.
// BM=96, BN=128, BK=64; grid = 384 M-tiles x 4 k-quarters = 1536 blocks (256 thr),
// 4 resident blocks/CU (launch_bounds(256,4); 112 VGPR incl. acc fits the 128 cap).
// 4 waves by oc-quarter: wave = 96m x 32oc x BK, acc[6][2] (round-6 geometry).
// W -> named regs dbuf from L2; A -> LDS dbuf 12KB/step via global_load_lds.
// Epilogue: atomicAdd into pre-zeroed out (4 commutative f32 contributions/element).
__global__ __launch_bounds__(256, 4) void gemm_kernel(const unsigned short* __restrict__ Phi,
                                                      const unsigned short* __restrict__ Wp,
                                                      float* __restrict__ out) {
    __shared__ __align__(16) unsigned char lds[24576]; // A dbuf 2 x 12KB
    int bid = blockIdx.x;
    int swz = (bid & 7) * 192 + (bid >> 3);   // XCD-bijective (1536 = 8*192)
    int tile = swz >> 2, kq = swz & 3;
    int m0 = tile * BM;
    int kt0 = kq * NSTEP;                     // 0, 21, 42, 63
    int tid = threadIdx.x;
    int lane = tid & 63;
    int wo = tid >> 6;                        // oc-quarter
    int lo = lane & 15, hi = lane >> 4, l7 = lane & 7;

    // A staging: 96 rows x 8 chunks = 768 chunks; thread stages rows r0, r0+32, r0+64.
    int s8 = tid & 7;
    int r0 = tid >> 3;
    int sx = s8 ^ (r0 & 7);                   // same for all three rows (32-spaced)
    size_t rowb[3];
#pragma unroll
    for (int i = 0; i < 3; ++i) {
        int n  = m0 + r0 + 32 * i;
        int b  = n / 2304;
        int u  = n - b * 2304;
        int du = u >> 2;                      // patches feature (c,kh,kw)
        int rr = u & 3;                       // 576-chunk within reinterpreted row
        int c  = du / 9;
        int tap = du - c * 9;
        int th = tap / 3, tw = tap - th * 3;
        rowb[i] = ((size_t)(b * C_IN + c) * 9) * PLANE + (size_t)((rr * 12 + th) * 50 + tw);
    }

    auto stageA = [&](int sel, int kt) {
        kt = min(kt, 80);                     // padded steps re-read A(80); W zero there
        int j  = kt / 9;
        int q0 = (kt - j * 9) << 6;
        int qs = q0 + sx * 8;
        int hq = qs / 48, wq = qs - hq * 48;  // 16B chunk never crosses 48-wrap
        size_t delta = (size_t)j * PLANE + (size_t)(hq * 50 + wq);
        unsigned char* pb = lds + sel * 12288;
#pragma unroll
        for (int i = 0; i < 3; ++i) {
            const unsigned short* src = Phi + rowb[i] + delta;
            __builtin_amdgcn_global_load_lds((const __attribute__((address_space(1))) void*)src,
                                             (__attribute__((address_space(3))) void*)(pb + i * 4096 + tid * 16), 16, 0, 0);
        }
    };

    const unsigned char* wsrc = (const unsigned char*)Wp + (size_t)wo * 4096 + (size_t)lane * 16;

#define LOADW(W00, W01, W10, W11, KT) do {                                  \
        const unsigned char* s_ = wsrc + (size_t)(KT) * 16384;              \
        W00 = *(const short8*)(s_);                                         \
        W01 = *(const short8*)(s_ + 1024);                                  \
        W10 = *(const short8*)(s_ + 2048);                                  \
        W11 = *(const short8*)(s_ + 3072);                                  \
    } while (0)

#define HALF(PB, SXR, WA, WB) do {                                          \
        short8 a0_ = *(const short8*)((PB) + ar0 + (SXR));                  \
        short8 a1_ = *(const short8*)((PB) + ar1 + (SXR));                  \
        short8 a2_ = *(const short8*)((PB) + ar2 + (SXR));                  \
        short8 a3_ = *(const short8*)((PB) + ar3 + (SXR));                  \
        short8 a4_ = *(const short8*)((PB) + ar4 + (SXR));                  \
        short8 a5_ = *(const short8*)((PB) + ar5 + (SXR));                  \
        __builtin_amdgcn_s_setprio(1);                                      \
        acc[0][0] = MFMA_BF16(a0_, WA, acc[0][0], 0, 0, 0);                 \
        acc[0][1] = MFMA_BF16(a0_, WB, acc[0][1], 0, 0, 0);                 \
        acc[1][0] = MFMA_BF16(a1_, WA, acc[1][0], 0, 0, 0);                 \
        acc[1][1] = MFMA_BF16(a1_, WB, acc[1][1], 0, 0, 0);                 \
        acc[2][0] = MFMA_BF16(a2_, WA, acc[2][0], 0, 0, 0);                 \
        acc[2][1] = MFMA_BF16(a2_, WB, acc[2][1], 0, 0, 0);                 \
        acc[3][0] = MFMA_BF16(a3_, WA, acc[3][0], 0, 0, 0);                 \
        acc[3][1] = MFMA_BF16(a3_, WB, acc[3][1], 0, 0, 0);                 \
        acc[4][0] = MFMA_BF16(a4_, WA, acc[4][0], 0, 0, 0);                 \
        acc[4][1] = MFMA_BF16(a4_, WB, acc[4][1], 0, 0, 0);                 \
        acc[5][0] = MFMA_BF16(a5_, WA, acc[5][0], 0, 0, 0);                 \
        acc[5][1] = MFMA_BF16(a5_, WB, acc[5][1], 0, 0, 0);                 \
        __builtin_amdgcn_s_setprio(0);                                      \
    } while (0)

#define COMPUTE(SEL, W00, W01, W10, W11) do {                               \
        const unsigned char* pb_ = lds + (SEL) * 12288;                     \
        HALF(pb_, sxr0, W00, W01);                                          \
        HALF(pb_, sxr1, W10, W11);                                          \
    } while (0)

    floatx4 acc[6][2];
    floatx4 zz = {0.f, 0.f, 0.f, 0.f};
#pragma unroll
    for (int a = 0; a < 6; ++a) { acc[a][0] = zz; acc[a][1] = zz; }

    int sxr0 = (hi ^ l7) << 4;               // k-slice 0 chunk slot (row&7 == lo&7)
    int sxr1 = ((4 + hi) ^ l7) << 4;         // k-slice 1
    int ar0 = (0 * 16 + lo) * 128, ar1 = (1 * 16 + lo) * 128, ar2 = (2 * 16 + lo) * 128;
    int ar3 = (3 * 16 + lo) * 128, ar4 = (4 * 16 + lo) * 128, ar5 = (5 * 16 + lo) * 128;

    short8 u00, u01, u10, u11, v00, v01, v10, v11;
    stageA(0, kt0);
    LOADW(u00, u01, u10, u11, kt0);
    __syncthreads();
    for (int t = 0; t < NSTEP - 1; t += 2) {
        stageA(1, kt0 + t + 1);
        LOADW(v00, v01, v10, v11, kt0 + t + 1);
        COMPUTE(0, u00, u01, u10, u11);
        __syncthreads();
        stageA(0, kt0 + t + 2);
        LOADW(u00, u01, u10, u11, kt0 + t + 2);
        COMPUTE(1, v00, v01, v10, v11);
        __syncthreads();
    }
    COMPUTE(0, u00, u01, u10, u11);           // step NSTEP-1

    // Epilogue: atomicAdd into pre-zeroed out; 4 commutative f32 contributions per
    // element (one per k-quarter). Ordering variance ~ulp, far under threshold.
#pragma unroll
    for (int fm = 0; fm < 6; ++fm) {
#pragma unroll
        for (int fo = 0; fo < 2; ++fo) {
            int oc = wo * 32 + fo * 16 + lo;
            int n0 = m0 + fm * 16 + hi * 4;
            float* op = out + (size_t)n0 * 128 + oc;
#pragma unroll
            for (int r = 0; r < 4; ++r)
                atomicAdd(op + (size_t)r * 128, acc[fm][fo][r]);
        }
    }
#undef LOADW
#undef HALF
#undef COMPUTE
}

extern "C" void kernel_launch(void* const* d_in, const int* in_sizes, int n_in,
                              void* d_out, int out_size, void* d_ws, size_t ws_size,
                              hipStream_t stream) {
    const float* x  = (const float*)d_in[0];
    const float* bw = (const float*)d_in[1];
    const float* sw = (const float*)d_in[2];
    const float* sc = (const float*)d_in[3];
    float* out = (float*)d_out;

    unsigned short* Wp  = (unsigned short*)d_ws;                         // 84*16KB = 1.31 MB
    unsigned short* Phi = (unsigned short*)((char*)d_ws + 1572864);      // 46.3 MB

    prep_kernel<<<1544, 256, 0, stream>>>(x, bw, sw, sc, Wp, Phi);
    hipMemsetAsync(out, 0, (size_t)out_size * sizeof(float), stream);
    gemm_kernel<<<1536, 256, 0, stream>>>(Phi, Wp, out);
}